// Round 3
// baseline (1433.142 us; speedup 1.0000x reference)
//
#include <hip/hip_runtime.h>
#include <hip/hip_bf16.h>

typedef __attribute__((ext_vector_type(8))) short short8;
typedef __attribute__((ext_vector_type(4))) float float4v;
typedef unsigned short ushort_t;

#define BB 512
#define SS 512
#define EE 20
#define H1C 30
#define H2C 50
#define NTC 45

// order LDS only; leave global loads in flight (no vmcnt drain).
// lgkmcnt(0) before s_barrier also guarantees this wave's LDS READS are
// complete before anyone passing the barrier overwrites those slots.
#define BAR() asm volatile("s_waitcnt lgkmcnt(0)\n\ts_barrier" ::: "memory")

#if __has_builtin(__builtin_amdgcn_exp2f)
#define EXP2(x) __builtin_amdgcn_exp2f(x)
#else
#define EXP2(x) exp2f(x)
#endif
#if __has_builtin(__builtin_amdgcn_rcpf)
#define RCPF(x) __builtin_amdgcn_rcpf(x)
#else
#define RCPF(x) (1.0f / (x))
#endif

#define LOG2E 1.4426950408889634f

__device__ __forceinline__ ushort_t f2bf(float f) {           // RNE f32->bf16 bits
    unsigned u = __float_as_uint(f);
    unsigned r = u + 0x7FFFu + ((u >> 16) & 1u);
    return (ushort_t)(r >> 16);
}
__device__ __forceinline__ float bf2f(ushort_t s) { return __uint_as_float(((unsigned)s) << 16); }

__device__ __forceinline__ float ldG(const void* p, int i, int f32) {
    if (f32) return ((const float*)p)[i];
    return bf2f(((const ushort_t*)p)[i]);
}
__device__ __forceinline__ int ldTok(const void* x, int i, int x64) {
    const int* xi = (const int*)x;
    return x64 ? xi[2 * i] : xi[i];
}

// LSTM activation. Gates arrive pre-scaled by LOG2E (i,f,o) / 2*LOG2E (g).
// Paired reciprocals: 1/di,1/df from one rcp of (di*df) (and dg,do likewise):
// 5 exp2 + 3 rcp per output instead of 5+5. Clamp keeps the pair product finite.
__device__ __forceinline__ float lstm_act(float gi, float gf, float gg, float go, float& c) {
    gi = fmaxf(gi, -30.f); gf = fmaxf(gf, -30.f);
    gg = fmaxf(gg, -30.f); go = fmaxf(go, -30.f);
    float di = 1.f + EXP2(-gi), df = 1.f + EXP2(-gf);
    float dg = 1.f + EXP2(-gg), dO = 1.f + EXP2(-go);
    float r1 = RCPF(di * df), r2 = RCPF(dg * dO);
    float si = df * r1, sf = di * r1;             // sigmoid(i), sigmoid(f)
    float tg = 2.f * (dO * r2) - 1.f;             // tanh(g)  (g pre-scaled 2x)
    float so = dg * r2;                           // sigmoid(o)
    float cc = sf * c + si * tg;
    c = cc;
    float e = EXP2(-2.8853900817779268f * cc);    // tanh(c)
    return so * (2.f * RCPF(1.f + e) - 1.f);
}

// ---------------- dtype detector: flags[0]=is_f32, flags[1]=is_x_int64 ----------------
__global__ void detect_kernel(const void* bih, const void* x, int* flags) {
    if (threadIdx.x == 0 && blockIdx.x == 0) {
        const ushort_t* u = (const ushort_t*)bih;
        int isf = 0;
        for (int i = 0; i < 120; i++) {
            float v = fabsf(bf2f(u[i]));
            if (!(v < 16.0f)) isf = 1;
        }
        flags[0] = isf;
        const int* xi = (const int*)x;
        int orv = 0;
        for (int i = 1; i < 32; i += 2) orv |= xi[i];
        flags[1] = (orv == 0) ? 1 : 0;
    }
}

// raw emb-row chunk (defer cvt to LDS-write time)
struct XR8 { uint4 a, b; };

__device__ __forceinline__ XR8 ldEmb8(const void* emb, int tok, int k0, int nelem, int f32v) {
    XR8 o;
    if (f32v) {
        const float* p = (const float*)emb + (size_t)tok * EE + k0;   // 16B aligned (80*tok + {0,32,64})
        o.a = *(const uint4*)p;
        o.b = (nelem == 8) ? *(const uint4*)(p + 4) : o.a;
    } else {
        const ushort_t* p = (const ushort_t*)emb + (size_t)tok * EE + k0;  // 8B aligned
        uint2 lo = *(const uint2*)p;
        o.a.x = lo.x; o.a.y = lo.y;
        if (nelem == 8) { uint2 hi = *(const uint2*)(p + 4); o.a.z = hi.x; o.a.w = hi.y; }
        else { o.a.z = 0; o.a.w = 0; }
        o.b = o.a;
    }
    return o;
}
__device__ __forceinline__ void writeX1(ushort_t* dst, const XR8& x, int nelem, int f32v) {
    if (f32v) {
        if (nelem == 8) {
            short8 s;
            s[0] = (short)f2bf(__uint_as_float(x.a.x)); s[1] = (short)f2bf(__uint_as_float(x.a.y));
            s[2] = (short)f2bf(__uint_as_float(x.a.z)); s[3] = (short)f2bf(__uint_as_float(x.a.w));
            s[4] = (short)f2bf(__uint_as_float(x.b.x)); s[5] = (short)f2bf(__uint_as_float(x.b.y));
            s[6] = (short)f2bf(__uint_as_float(x.b.z)); s[7] = (short)f2bf(__uint_as_float(x.b.w));
            *(short8*)dst = s;
        } else {
            ushort4 u;
            u.x = f2bf(__uint_as_float(x.a.x)); u.y = f2bf(__uint_as_float(x.a.y));
            u.z = f2bf(__uint_as_float(x.a.z)); u.w = f2bf(__uint_as_float(x.a.w));
            *(ushort4*)dst = u;
        }
    } else {
        if (nelem == 8) *(uint4*)dst = x.a;          // already bf16 bits
        else { uint2 t; t.x = x.a.x; t.y = x.a.y; *(uint2*)dst = t; }
    }
}

// =========================================================================================
// Layer 1. grid 64 = one chain (dir, 16-batch-block) per WG; block 256 = 4 waves on the
// CU's 4 SIMDs. Swapped-operand MFMA: A = W[n][k] (gate rows), B = data[k][m] -> D[n][m].
// Wave w computes gate w (8 MFMAs/step). Gates exchanged via f32 LDS; activations
// redistributed: every lane does 2 outputs (n = w*8+quad*2+{0,1}, m = li) -> trans work
// spread over all 4 SIMDs. Two barriers/step. x-projection pipelined one step ahead.
// LDS h/x tiles [16 m][48 kslots] (96B stride: 4-way max conflict on b128 reads).
// =========================================================================================
__global__ __launch_bounds__(256, 1) void lstm1_kernel(
    const void* __restrict__ x,
    const void* __restrict__ emb_f, const void* __restrict__ emb_b,
    const void* __restrict__ h0_f, const void* __restrict__ c0_f,
    const void* __restrict__ Wih_f, const void* __restrict__ Whh_f,
    const void* __restrict__ bih_f, const void* __restrict__ bhh_f,
    const void* __restrict__ h0_b, const void* __restrict__ c0_b,
    const void* __restrict__ Wih_b, const void* __restrict__ Whh_b,
    const void* __restrict__ bih_b, const void* __restrict__ bhh_b,
    ushort_t* __restrict__ hsf, ushort_t* __restrict__ hsb,
    const int* __restrict__ flags)
{
    const int f32v = flags[0], x64 = flags[1];
    const int tid = threadIdx.x;
    const int cg = blockIdx.x, dir = cg >> 5, j0 = (cg & 31) << 4;
    const int w = tid >> 6, lane = tid & 63, li = lane & 15, quad = lane >> 4;

    const void* emb = dir ? emb_b : emb_f;
    const void* h0  = dir ? h0_b  : h0_f;
    const void* c0  = dir ? c0_b  : c0_f;
    const void* Wih = dir ? Wih_b : Wih_f;
    const void* Whh = dir ? Whh_b : Whh_f;
    const void* bih = dir ? bih_b : bih_f;
    const void* bhh = dir ? bhh_b : bhh_f;
    ushort_t* hs = dir ? hsb : hsf;

    __shared__ int toks[16][SS];                        // 32KB token table
    __shared__ __align__(16) ushort_t Xs[2][16][48];    // x staging, dbuf
    __shared__ __align__(16) ushort_t Hs[16][48];       // h, single buffer (BAR1 orders RAW)
    __shared__ float Gs[4][16][33];                     // gate exchange, f32, pad 33

    for (int idx = tid; idx < 16 * SS; idx += 256) {
        int r = idx >> 9, t = idx & (SS - 1);
        toks[r][t] = ldTok(x, (j0 + r) * SS + t, x64);
    }
    for (int idx = tid; idx < 2 * 16 * 48; idx += 256) ((ushort_t*)Xs)[idx] = 0;
    for (int idx = tid; idx < 16 * 48; idx += 256) ((ushort_t*)Hs)[idx] = 0;

    // ---- MFMA role: wave w = gate w. A-frag: lane holds W[n = u*16+li][k = quad*8+j] ----
    const float sc = (w == 2) ? 2.0f * LOG2E : LOG2E;   // fold exp2 scale into weights
    short8 whh_h[2], whh_l[2], wxh_[2], wxl_[2];
    float4v biasv[2];
    #pragma unroll
    for (int u = 0; u < 2; u++) {
        const int n = u * 16 + li;
        const bool nok = n < H1C;
        #pragma unroll
        for (int r = 0; r < 4; r++) {                   // C row = quad*4+r
            int nn = u * 16 + quad * 4 + r;
            biasv[u][r] = (nn < H1C) ? sc * (ldG(bih, w * H1C + nn, f32v) + ldG(bhh, w * H1C + nn, f32v)) : 0.f;
        }
        short8 hh, hl, xh, xl;
        #pragma unroll
        for (int j = 0; j < 8; j++) {
            const int k = quad * 8 + j;
            float wh = (nok && k < H1C) ? sc * ldG(Whh, (w * H1C + n) * H1C + k, f32v) : 0.f;
            ushort_t b1 = f2bf(wh); hh[j] = (short)b1; hl[j] = (short)f2bf(wh - bf2f(b1));
            float wx = (nok && k < EE) ? sc * ldG(Wih, (w * H1C + n) * EE + k, f32v) : 0.f;
            ushort_t b2 = f2bf(wx); xh[j] = (short)b2; xl[j] = (short)f2bf(wx - bf2f(b2));
        }
        whh_h[u] = hh; whh_l[u] = hl; wxh_[u] = xh; wxl_[u] = xl;
    }

    // ---- act role: lane owns outputs (m = li, n = anb, anb+1) ----
    const int am = li, anb = w * 8 + quad * 2;          // bijective over n 0..31
    // ---- loader role: 12 lanes/wave: row lm, chunk lch ----
    const int lm = w * 4 + quad, lch = li;
    const bool ldr = li < 3;
    const int lk0 = lch * 8, lnel = (lch == 2) ? 4 : 8;
    const int t0 = dir ? SS - 1 : 0, dt = dir ? -1 : 1;

    __syncthreads();   // toks + zeros visible

    float cr0, cr1;
    {
        const int n0 = anb, n1 = anb + 1;
        cr0 = (n0 < H1C) ? ldG(c0, (j0 + am) * H1C + n0, f32v) : 0.f;
        cr1 = (n1 < H1C) ? ldG(c0, (j0 + am) * H1C + n1, f32v) : 0.f;
        unsigned ha = (n0 < H1C) ? f2bf(ldG(h0, (j0 + am) * H1C + n0, f32v)) : 0;
        unsigned hb = (n1 < H1C) ? f2bf(ldG(h0, (j0 + am) * H1C + n1, f32v)) : 0;
        *(unsigned*)&Hs[am][anb] = ha | (hb << 16);
    }
    XR8 embA = {}, embB = {}; int tokA = 0, tokB = 0;
    if (ldr) {
        XR8 e0 = ldEmb8(emb, toks[lm][t0], lk0, lnel, f32v);
        writeX1(&Xs[0][lm][lk0], e0, lnel, f32v);
        XR8 e1 = ldEmb8(emb, toks[lm][t0 + dt], lk0, lnel, f32v);
        writeX1(&Xs[1][lm][lk0], e1, lnel, f32v);
        embA = ldEmb8(emb, toks[lm][t0 + 2 * dt], lk0, lnel, f32v);   // x(t0+2dt) raw
        tokA = toks[lm][t0 + 3 * dt];                                  // tok(t0+3dt)
    }
    __syncthreads();   // Hs, Xs[0], Xs[1] visible

    float4v xacc[2];   // xacc(t) = bias + Wx*x(t), computed one step ahead
    {
        short8 xf = *(const short8*)&Xs[0][li][quad * 8];
        #pragma unroll
        for (int u = 0; u < 2; u++) {
            float4v b = biasv[u];
            b = __builtin_amdgcn_mfma_f32_16x16x32_bf16(wxh_[u], xf, b, 0, 0, 0);
            b = __builtin_amdgcn_mfma_f32_16x16x32_bf16(wxl_[u], xf, b, 0, 0, 0);
            xacc[u] = b;
        }
    }

    auto step = [&](int it, XR8& ein, XR8& eout, int& tin, int& tout) {
        const int t = t0 + dt * it;
        // phase A: MFMA (gates of step t; x-projection of step t+1)
        short8 hf = *(const short8*)&Hs[li][quad * 8];
        short8 xf = *(const short8*)&Xs[(it + 1) & 1][li][quad * 8];
        float4v acc[2], xn[2];
        #pragma unroll
        for (int u = 0; u < 2; u++) {
            float4v a = xacc[u];
            a = __builtin_amdgcn_mfma_f32_16x16x32_bf16(whh_h[u], hf, a, 0, 0, 0);
            a = __builtin_amdgcn_mfma_f32_16x16x32_bf16(whh_l[u], hf, a, 0, 0, 0);
            acc[u] = a;
            float4v b = biasv[u];
            b = __builtin_amdgcn_mfma_f32_16x16x32_bf16(wxh_[u], xf, b, 0, 0, 0);
            b = __builtin_amdgcn_mfma_f32_16x16x32_bf16(wxl_[u], xf, b, 0, 0, 0);
            xn[u] = b;
        }
        // phase B: publish gates (f32)
        #pragma unroll
        for (int u = 0; u < 2; u++) {
            #pragma unroll
            for (int r = 0; r < 4; r++)
                Gs[w][li][u * 16 + quad * 4 + r] = acc[u][r];
        }
        BAR();
        // phase C: activations, 2 outputs/lane; h -> LDS (packed b32) + global (packed b32)
        float gi0 = Gs[0][am][anb], gi1 = Gs[0][am][anb + 1];
        float gf0 = Gs[1][am][anb], gf1 = Gs[1][am][anb + 1];
        float gg0 = Gs[2][am][anb], gg1 = Gs[2][am][anb + 1];
        float go0 = Gs[3][am][anb], go1 = Gs[3][am][anb + 1];
        float h0v = lstm_act(gi0, gf0, gg0, go0, cr0);
        float h1v = lstm_act(gi1, gf1, gg1, go1, cr1);
        unsigned hp = (unsigned)f2bf(h0v) | ((unsigned)f2bf(h1v) << 16);
        *(unsigned*)&Hs[am][anb] = hp;
        *(unsigned*)&hs[((size_t)(j0 + am) * SS + t) * 32 + anb] = hp;
        // loaders: stage x(t+2), issue emb(t+3), read tok(t+4)
        if (ldr) {
            if (it + 2 < SS) writeX1(&Xs[it & 1][lm][lk0], ein, lnel, f32v);
            if (it + 3 < SS) eout = ldEmb8(emb, tin, lk0, lnel, f32v);
            if (it + 4 < SS) tout = toks[lm][t0 + dt * (it + 4)];
        }
        #pragma unroll
        for (int u = 0; u < 2; u++) xacc[u] = xn[u];
        BAR();
    };
    for (int it = 0; it < SS; it += 2) { step(it, embA, embB, tokA, tokB); step(it + 1, embB, embA, tokB, tokA); }
}

// =========================================================================================
// Layer 2. Same 4-wave gate-split structure. grid 64, block 256. Wave w = gate w:
// 4 n-tiles x 2 k-tiles x hi/lo = 16 h-MFMAs + 16 x-MFMAs per step. K: x k 0..29 = f,
// 32..61 = b; h k 0..49. Activations packed-linear: out = s*256+tid (s=0..3, n=s*16+tid/16,
// valid n<50) -> <=4 outputs/lane, waves balanced 13/13/13/11 outputs per n-column group.
// LDS tiles [16 m][112 kslots] (224B stride). hs2T layout [c][64][batch] unchanged.
// =========================================================================================
__global__ __launch_bounds__(256, 1) void lstm2_kernel(
    const ushort_t* __restrict__ hs1f, const ushort_t* __restrict__ hs1b,
    const void* __restrict__ h0_f, const void* __restrict__ c0_f,
    const void* __restrict__ Wih_f, const void* __restrict__ Whh_f,
    const void* __restrict__ bih_f, const void* __restrict__ bhh_f,
    const void* __restrict__ h0_b, const void* __restrict__ c0_b,
    const void* __restrict__ Wih_b, const void* __restrict__ Whh_b,
    const void* __restrict__ bih_b, const void* __restrict__ bhh_b,
    ushort_t* __restrict__ hsf, ushort_t* __restrict__ hsb,
    const int* __restrict__ flags)
{
    const int f32v = flags[0];
    const int tid = threadIdx.x;
    const int cg = blockIdx.x, dir = cg >> 5, cb = (cg & 31) << 4;
    const int w = tid >> 6, lane = tid & 63, li = lane & 15, quad = lane >> 4;

    const void* h0  = dir ? h0_b  : h0_f;
    const void* c0  = dir ? c0_b  : c0_f;
    const void* Wih = dir ? Wih_b : Wih_f;
    const void* Whh = dir ? Whh_b : Whh_f;
    const void* bih = dir ? bih_b : bih_f;
    const void* bhh = dir ? bhh_b : bhh_f;
    ushort_t* hs = dir ? hsb : hsf;

    __shared__ __align__(16) ushort_t Xs[2][16][112];   // x staging, dbuf (224B stride)
    __shared__ __align__(16) ushort_t Hs[16][112];      // h, single buffer
    __shared__ float Gs[4][16][65];                     // gate exchange, pad 65

    for (int idx = tid; idx < 2 * 16 * 112; idx += 256) ((ushort_t*)Xs)[idx] = 0;
    for (int idx = tid; idx < 16 * 112; idx += 256) ((ushort_t*)Hs)[idx] = 0;

    const float sc = (w == 2) ? 2.0f * LOG2E : LOG2E;
    short8 wh_h[4][2], wh_l[4][2], wx_h[4][2], wx_l[4][2];
    float4v biasv[4];
    #pragma unroll
    for (int u = 0; u < 4; u++) {
        const int n = u * 16 + li;
        const bool nok = n < H2C;
        #pragma unroll
        for (int r = 0; r < 4; r++) {
            int nn = u * 16 + quad * 4 + r;
            biasv[u][r] = (nn < H2C) ? sc * (ldG(bih, w * H2C + nn, f32v) + ldG(bhh, w * H2C + nn, f32v)) : 0.f;
        }
        #pragma unroll
        for (int kt = 0; kt < 2; kt++) {
            short8 hh, hl, xh, xl;
            #pragma unroll
            for (int j = 0; j < 8; j++) {
                const int k = kt * 32 + quad * 8 + j;
                float wh = (nok && k < H2C) ? sc * ldG(Whh, (w * H2C + n) * H2C + k, f32v) : 0.f;
                ushort_t b1 = f2bf(wh); hh[j] = (short)b1; hl[j] = (short)f2bf(wh - bf2f(b1));
                float wx = 0.f;
                if (nok) {
                    if (k < H1C) wx = ldG(Wih, (w * H2C + n) * (2 * H1C) + k, f32v);
                    else if (k >= 32 && k < 32 + H1C) wx = ldG(Wih, (w * H2C + n) * (2 * H1C) + H1C + (k - 32), f32v);
                }
                wx *= sc;
                ushort_t b2 = f2bf(wx); xh[j] = (short)b2; xl[j] = (short)f2bf(wx - bf2f(b2));
            }
            wh_h[u][kt] = hh; wh_l[u][kt] = hl; wx_h[u][kt] = xh; wx_l[u][kt] = xl;
        }
    }

    // act role: out = s*256 + tid -> n = s*16 + (tid>>4), m = tid&15 (valid n<50)
    const int am = tid & 15, anq = tid >> 4;
    // loader role: tid<128: row lm, 16B chunk lch (0..3 from f, 4..7 from b)
    const bool ldr = tid < 128;
    const int lm = tid & 15, lch = (tid >> 4) & 7;
    const int t0 = dir ? SS - 1 : 0, dt = dir ? -1 : 1;

    auto loadXraw = [&](int cc) -> uint4 {
        if (lch < 4) return *(const uint4*)&hs1f[((size_t)cc * SS + (cb + lm)) * 32 + lch * 8];
        return *(const uint4*)&hs1b[((size_t)cc * SS + (SS - 1 - (cb + lm))) * 32 + (lch - 4) * 8];
    };

    __syncthreads();   // zeros visible

    float creg[4] = {0.f, 0.f, 0.f, 0.f};
    #pragma unroll
    for (int s = 0; s < 4; s++) {
        const int n = s * 16 + anq;
        if (n < H2C) {
            creg[s] = ldG(c0, (cb + am) * H2C + n, f32v);
            Hs[am][n] = f2bf(ldG(h0, (cb + am) * H2C + n, f32v));
        }
    }
    uint4 xrA = {}, xrB = {};
    if (ldr) {
        *(uint4*)&Xs[0][lm][lch * 8] = loadXraw(t0);
        *(uint4*)&Xs[1][lm][lch * 8] = loadXraw(t0 + dt);
        xrA = loadXraw(t0 + 2 * dt);
    }
    __syncthreads();   // Hs, Xs[0], Xs[1] visible

    float4v xacc[4];
    {
        short8 xf0 = *(const short8*)&Xs[0][li][quad * 8];
        short8 xf1 = *(const short8*)&Xs[0][li][32 + quad * 8];
        #pragma unroll
        for (int u = 0; u < 4; u++) {
            float4v b = biasv[u];
            b = __builtin_amdgcn_mfma_f32_16x16x32_bf16(wx_h[u][0], xf0, b, 0, 0, 0);
            b = __builtin_amdgcn_mfma_f32_16x16x32_bf16(wx_l[u][0], xf0, b, 0, 0, 0);
            b = __builtin_amdgcn_mfma_f32_16x16x32_bf16(wx_h[u][1], xf1, b, 0, 0, 0);
            b = __builtin_amdgcn_mfma_f32_16x16x32_bf16(wx_l[u][1], xf1, b, 0, 0, 0);
            xacc[u] = b;
        }
    }

    auto step = [&](int it, uint4& xin, uint4& xout) {
        const int t = t0 + dt * it;
        // phase A
        short8 hf0 = *(const short8*)&Hs[li][quad * 8];
        short8 hf1 = *(const short8*)&Hs[li][32 + quad * 8];
        short8 xf0 = *(const short8*)&Xs[(it + 1) & 1][li][quad * 8];
        short8 xf1 = *(const short8*)&Xs[(it + 1) & 1][li][32 + quad * 8];
        float4v acc[4], xn[4];
        #pragma unroll
        for (int u = 0; u < 4; u++) {
            float4v a = xacc[u];
            a = __builtin_amdgcn_mfma_f32_16x16x32_bf16(wh_h[u][0], hf0, a, 0, 0, 0);
            a = __builtin_amdgcn_mfma_f32_16x16x32_bf16(wh_l[u][0], hf0, a, 0, 0, 0);
            a = __builtin_amdgcn_mfma_f32_16x16x32_bf16(wh_h[u][1], hf1, a, 0, 0, 0);
            a = __builtin_amdgcn_mfma_f32_16x16x32_bf16(wh_l[u][1], hf1, a, 0, 0, 0);
            acc[u] = a;
            float4v b = biasv[u];
            b = __builtin_amdgcn_mfma_f32_16x16x32_bf16(wx_h[u][0], xf0, b, 0, 0, 0);
            b = __builtin_amdgcn_mfma_f32_16x16x32_bf16(wx_l[u][0], xf0, b, 0, 0, 0);
            b = __builtin_amdgcn_mfma_f32_16x16x32_bf16(wx_h[u][1], xf1, b, 0, 0, 0);
            b = __builtin_amdgcn_mfma_f32_16x16x32_bf16(wx_l[u][1], xf1, b, 0, 0, 0);
            xn[u] = b;
        }
        // phase B
        #pragma unroll
        for (int u = 0; u < 4; u++) {
            #pragma unroll
            for (int r = 0; r < 4; r++)
                Gs[w][li][u * 16 + quad * 4 + r] = acc[u][r];
        }
        BAR();
        // phase C: <=4 outputs/lane
        #pragma unroll
        for (int s = 0; s < 4; s++) {
            const int n = s * 16 + anq;
            if (n < H2C) {
                float gi = Gs[0][am][n], gf = Gs[1][am][n], gg = Gs[2][am][n], go = Gs[3][am][n];
                float hv = lstm_act(gi, gf, gg, go, creg[s]);
                ushort_t hb = f2bf(hv);
                Hs[am][n] = hb;
                hs[((size_t)t * 64 + n) * SS + cb + am] = hb;
            }
        }
        if (ldr) {
            if (it + 2 < SS) *(uint4*)&Xs[it & 1][lm][lch * 8] = xin;
            if (it + 3 < SS) xout = loadXraw(t0 + dt * (it + 3));
        }
        #pragma unroll
        for (int u = 0; u < 4; u++) xacc[u] = xn[u];
        BAR();
    };
    for (int it = 0; it < SS; it += 2) { step(it, xrA, xrB); step(it + 1, xrB, xrA); }
}

// =========================================================================================
// Final linear (MFMA GEMM). out[i,j,:] = concat(hs2fT[i][:][j], hs2bT[511-i][:][j]) @ lw^T + lb
// WG = 64 pairs (fixed i, j-block of 64). K pad 128: k<50 f, 64..113 b.  (unchanged)
// =========================================================================================
__global__ __launch_bounds__(256) void lin_kernel(
    const ushort_t* __restrict__ hs2f, const ushort_t* __restrict__ hs2b,
    const void* __restrict__ lw, const void* __restrict__ lb,
    void* __restrict__ out, const int* __restrict__ flags)
{
    const int f32v = flags[0];
    const int tid = threadIdx.x, wave = tid >> 6, lane = tid & 63, li = lane & 15, quad = lane >> 4;

    __shared__ __align__(16) ushort_t Af[4][4][64][8];   // [wb][kt][kg*16+row][j]
    for (int idx = tid; idx < 4 * 4 * 64 * 8; idx += 256) ((ushort_t*)Af)[idx] = 0;

    short8 bhi[3][4], blo[3][4];
    float biasv[3];
    #pragma unroll
    for (int nt = 0; nt < 3; nt++) {
        const int nn = nt * 16 + li;
        const bool nok = nn < NTC;
        biasv[nt] = nok ? ldG(lb, nn, f32v) : 0.f;
        #pragma unroll
        for (int kt = 0; kt < 4; kt++) {
            short8 hi, lo;
            #pragma unroll
            for (int j = 0; j < 8; j++) {
                int k = kt * 32 + quad * 8 + j;
                float w = 0.f;
                if (nok) {
                    if (k < H2C) w = ldG(lw, nn * 100 + k, f32v);
                    else if (k >= 64 && k < 64 + H2C) w = ldG(lw, nn * 100 + 50 + (k - 64), f32v);
                }
                ushort_t h = f2bf(w);
                hi[j] = (short)h;
                lo[j] = (short)f2bf(w - bf2f(h));
            }
            bhi[nt][kt] = hi; blo[nt][kt] = lo;
        }
    }

    const int P0 = blockIdx.x * 64;
    const int i = P0 >> 9, j0 = P0 & 511;
    __syncthreads();   // Af zero
    for (int idx = tid; idx < 100 * 32; idx += 256) {
        const int kk = idx >> 5, pj = (idx & 31) * 2;
        unsigned v;
        int k;
        if (kk < H2C) {
            v = *(const unsigned*)&hs2f[((size_t)i * 64 + kk) * SS + j0 + pj];
            k = kk;
        } else {
            v = *(const unsigned*)&hs2b[((size_t)(SS - 1 - i) * 64 + (kk - H2C)) * SS + j0 + pj];
            k = 64 + (kk - H2C);
        }
        const int kt = k >> 5, kg = (k & 31) >> 3, j = k & 7;
        Af[pj >> 4][kt][kg * 16 + (pj & 15)][j] = (ushort_t)(v & 0xFFFF);
        Af[pj >> 4][kt][kg * 16 + ((pj + 1) & 15)][j] = (ushort_t)(v >> 16);
    }
    __syncthreads();

    short8 af[4];
    #pragma unroll
    for (int kt = 0; kt < 4; kt++) af[kt] = *(const short8*)&Af[wave][kt][lane][0];
    #pragma unroll
    for (int nt = 0; nt < 3; nt++) {
        float4v a; a[0] = a[1] = a[2] = a[3] = biasv[nt];
        #pragma unroll
        for (int kt = 0; kt < 4; kt++) {
            a = __builtin_amdgcn_mfma_f32_16x16x32_bf16(af[kt], bhi[nt][kt], a, 0, 0, 0);
            a = __builtin_amdgcn_mfma_f32_16x16x32_bf16(af[kt], blo[nt][kt], a, 0, 0, 0);
        }
        const int nn = nt * 16 + li;
        if (nn < NTC) {
            #pragma unroll
            for (int reg = 0; reg < 4; reg++) {
                const int prow = wave * 16 + quad * 4 + reg;
                const size_t op = (size_t)(P0 + prow) * NTC + nn;
                if (f32v) ((float*)out)[op] = a[reg];
                else      ((ushort_t*)out)[op] = f2bf(a[reg]);
            }
        }
    }
}

extern "C" void kernel_launch(void* const* d_in, const int* in_sizes, int n_in,
                              void* d_out, int out_size, void* d_ws, size_t ws_size,
                              hipStream_t stream)
{
    const void* x      = d_in[0];
    const void* emb_f1 = d_in[1];
    const void* emb_b1 = d_in[2];
    const void* h0_f1  = d_in[3];
    const void* c0_f1  = d_in[4];
    const void* Wih_f1 = d_in[5];
    const void* Whh_f1 = d_in[6];
    const void* bih_f1 = d_in[7];
    const void* bhh_f1 = d_in[8];
    const void* h0_b1  = d_in[9];
    const void* c0_b1  = d_in[10];
    const void* Wih_b1 = d_in[11];
    const void* Whh_b1 = d_in[12];
    const void* bih_b1 = d_in[13];
    const void* bhh_b1 = d_in[14];
    const void* h0_f2  = d_in[15];
    const void* c0_f2  = d_in[16];
    const void* Wih_f2 = d_in[17];
    const void* Whh_f2 = d_in[18];
    const void* bih_f2 = d_in[19];
    const void* bhh_f2 = d_in[20];
    const void* h0_b2  = d_in[21];
    const void* c0_b2  = d_in[22];
    const void* Wih_b2 = d_in[23];
    const void* Whh_b2 = d_in[24];
    const void* bih_b2 = d_in[25];
    const void* bhh_b2 = d_in[26];
    const void* lin_w  = d_in[27];
    const void* lin_b  = d_in[28];

    // ws: flags(256B) | hs1Pf | hs1Pb ([512][512][32] bf16 each, 16.8MB)
    //                 | hs2fT | hs2bT ([512][64][512] bf16 each, 33.6MB)   total ~101MB
    int* flags = (int*)d_ws;
    ushort_t* hs1f = (ushort_t*)((char*)d_ws + 256);
    ushort_t* hs1b = hs1f + (size_t)BB * SS * 32;
    ushort_t* hs2f = hs1b + (size_t)BB * SS * 32;
    ushort_t* hs2b = hs2f + (size_t)SS * 64 * BB;

    detect_kernel<<<1, 64, 0, stream>>>(bih_f1, x, flags);
    lstm1_kernel<<<64, 256, 0, stream>>>(x, emb_f1, emb_b1,
        h0_f1, c0_f1, Wih_f1, Whh_f1, bih_f1, bhh_f1,
        h0_b1, c0_b1, Wih_b1, Whh_b1, bih_b1, bhh_b1, hs1f, hs1b, flags);
    lstm2_kernel<<<64, 256, 0, stream>>>(hs1f, hs1b,
        h0_f2, c0_f2, Wih_f2, Whh_f2, bih_f2, bhh_f2,
        h0_b2, c0_b2, Wih_b2, Whh_b2, bih_b2, bhh_b2, hs2f, hs2b, flags);
    lin_kernel<<<(BB * SS) / 64, 256, 0, stream>>>(hs2f, hs2b, lin_w, lin_b, d_out, flags);
}